// Round 4
// baseline (914.627 us; speedup 1.0000x reference)
//
#include <hip/hip_runtime.h>

#define NN 50000
#define NE 1600000
#define CLAMP_V 5.0f
#define GRP 2                 // nodes per work group (one wave owns a group)
#define NGROUPS ((NN + GRP - 1) / GRP)

typedef __attribute__((ext_vector_type(4))) short bf16x4;
typedef __attribute__((ext_vector_type(4))) float f32x4;

static __device__ __forceinline__ short f2bf(float x) {
    unsigned u = __builtin_bit_cast(unsigned, x);
    u += 0x7FFF + ((u >> 16) & 1);   // round-to-nearest-even
    return (short)(u >> 16);
}

__global__ __launch_bounds__(256) void proj_kernel(
    const float* __restrict__ x,
    const float* __restrict__ WQ, const float* __restrict__ bQ,
    const float* __restrict__ WK, const float* __restrict__ WVw,
    float* __restrict__ Q, float* __restrict__ K, float* __restrict__ V)
{
    __shared__ float sWQ[4096], sWK[4096], sWV[4096];
    for (int i = threadIdx.x; i < 4096; i += 256) {
        sWQ[i] = WQ[i]; sWK[i] = WK[i]; sWV[i] = WVw[i];
    }
    __syncthreads();
    const int col = threadIdx.x & 63;
    const int nl  = threadIdx.x >> 6;
    const float bq = bQ[col];
    for (int node = blockIdx.x * 4 + nl; node < NN; node += gridDim.x * 4) {
        const float* xr = x + (size_t)node * 64;
        float aq = 0.f, ak = 0.f, av = 0.f;
        #pragma unroll
        for (int j = 0; j < 64; ++j) {
            float xv = xr[j];
            aq = fmaf(xv, sWQ[j*64+col], aq);
            ak = fmaf(xv, sWK[j*64+col], ak);
            av = fmaf(xv, sWV[j*64+col], av);
        }
        Q[(size_t)node*64+col] = aq + bq;
        K[(size_t)node*64+col] = ak;
        V[(size_t)node*64+col] = av;
    }
}

__global__ __launch_bounds__(256) void hist_kernel(
    const int* __restrict__ ei, int* __restrict__ counts)
{
    for (int e = blockIdx.x * 256 + threadIdx.x; e < NE; e += gridDim.x * 256)
        atomicAdd(&counts[ei[NE + e]], 1);
}

__global__ __launch_bounds__(1024) void scan_kernel(
    const int* __restrict__ counts, int* __restrict__ row_ptr,
    int* __restrict__ cursor)
{
    __shared__ int buf[1024];
    __shared__ int offset_s;
    const int tid = threadIdx.x;
    if (tid == 0) offset_s = 0;
    __syncthreads();
    for (int base = 0; base < NN; base += 1024) {
        const int i = base + tid;
        int v = (i < NN) ? counts[i] : 0;
        buf[tid] = v; __syncthreads();
        #pragma unroll
        for (int d = 1; d < 1024; d <<= 1) {
            int t = (tid >= d) ? buf[tid - d] : 0;
            __syncthreads();
            buf[tid] += t;
            __syncthreads();
        }
        const int excl = buf[tid] - v;
        if (i < NN) { int rp = offset_s + excl; row_ptr[i] = rp; cursor[i] = rp; }
        __syncthreads();
        if (tid == 1023) offset_s += buf[1023];
        __syncthreads();
    }
    if (tid == 1023) row_ptr[NN] = offset_s;   // == NE
}

__global__ __launch_bounds__(256) void scatter_kernel(
    const int* __restrict__ ei, int* __restrict__ cursor,
    int* __restrict__ sortedE, int2* __restrict__ sortedSD)
{
    for (int e = blockIdx.x * 256 + threadIdx.x; e < NE; e += gridDim.x * 256) {
        int src = ei[e], dst = ei[NE + e];
        int pos = atomicAdd(&cursor[dst], 1);
        sortedE[pos] = e;
        sortedSD[pos] = make_int2(src, dst);
    }
}

// One wave per node-group: MFMA E over 16 sorted edges, score, register-
// accumulate num/den per node, write wV rows directly. No fp atomics.
__global__ __launch_bounds__(256) void edge_sorted_kernel(
    const float* __restrict__ edge_attr,
    const float* __restrict__ WE1, const float* __restrict__ bE1,
    const int* __restrict__ sortedE, const int2* __restrict__ sortedSD,
    const int* __restrict__ row_ptr,
    const float* __restrict__ Q, const float* __restrict__ K,
    const float* __restrict__ V,
    float* __restrict__ wE, float* __restrict__ wV, int* __restrict__ workCtr)
{
    __shared__ float Elds[4][16 * 65];
    const int tid  = threadIdx.x;
    const int wv   = tid >> 6;
    const int lane = tid & 63;
    const int g    = lane >> 4;
    const int rowl = lane & 15;

    // B fragments of WE1 (bf16) + bias
    bf16x4 bF[4][4];
    float  bias[4];
    #pragma unroll
    for (int cb = 0; cb < 4; ++cb) {
        const int col = rowl + 16 * cb;
        bias[cb] = bE1[col];
        #pragma unroll
        for (int ks = 0; ks < 4; ++ks) {
            bf16x4 t;
            #pragma unroll
            for (int j = 0; j < 4; ++j)
                t[j] = f2bf(WE1[(ks * 16 + g * 4 + j) * 64 + col]);
            bF[cb][ks] = t;
        }
    }

    const float inv_sqrt8 = 0.35355339059327373f;

    for (;;) {
        int grp;
        if (lane == 0) grp = atomicAdd(workCtr, 1);
        grp = __shfl(grp, 0);
        if (grp >= NGROUPS) break;

        const int n0 = grp * GRP;
        const int n1 = (n0 + GRP < NN) ? n0 + GRP : NN;
        const int eS = row_ptr[n0];
        const int eE = row_ptr[n1];

        int   cur = -1;
        float num = 0.f, den = 0.f, Qv = 0.f;

        for (int base = eS; base < eE; base += 16) {
            const int cnt = (eE - base < 16) ? (eE - base) : 16;

            // gather A fragments (16 sorted edge rows, 256B each)
            const int er = sortedE[base + (rowl < cnt ? rowl : cnt - 1)];
            const float* ar = edge_attr + (size_t)er * 64 + g * 4;
            bf16x4 aF[4];
            #pragma unroll
            for (int ks = 0; ks < 4; ++ks) {
                f32x4 vv = *reinterpret_cast<const f32x4*>(ar + ks * 16);
                bf16x4 t;
                #pragma unroll
                for (int j = 0; j < 4; ++j) t[j] = f2bf(vv[j]);
                aF[ks] = t;
            }

            f32x4 acc[4];
            #pragma unroll
            for (int cb = 0; cb < 4; ++cb) {
                acc[cb][0] = bias[cb]; acc[cb][1] = bias[cb];
                acc[cb][2] = bias[cb]; acc[cb][3] = bias[cb];
            }
            #pragma unroll
            for (int cb = 0; cb < 4; ++cb)
                #pragma unroll
                for (int ks = 0; ks < 4; ++ks)
                    acc[cb] = __builtin_amdgcn_mfma_f32_16x16x16bf16_1k(
                        aF[ks], bF[cb][ks], acc[cb], 0, 0, 0);

            #pragma unroll
            for (int cb = 0; cb < 4; ++cb)
                #pragma unroll
                for (int r = 0; r < 4; ++r)
                    Elds[wv][(g * 4 + r) * 65 + rowl + 16 * cb] = acc[cb][r];

            #pragma unroll 4
            for (int el = 0; el < cnt; ++el) {
                const int i = base + el;
                const int2 sd = sortedSD[i];
                const int src = sd.x, dst = sd.y;
                if (dst != cur) {                       // wave-uniform branch
                    if (cur >= 0)
                        wV[(size_t)cur * 64 + lane] = num / (den + 1e-16f);
                    for (int z = (cur < 0 ? n0 : cur + 1); z < dst; ++z)
                        wV[(size_t)z * 64 + lane] = 0.f;
                    cur = dst; num = 0.f; den = 0.f;
                    Qv = Q[(size_t)dst * 64 + lane];
                }
                const int eo = sortedE[i];
                const float Kv = K[(size_t)src * 64 + lane];
                const float Vv = V[(size_t)src * 64 + lane];
                const float El = Elds[wv][el * 65 + lane];
                const float sc = Kv * Qv * El;
                wE[(size_t)eo * 64 + lane] = sc;
                float ss = sc;
                ss += __shfl_xor(ss, 1);
                ss += __shfl_xor(ss, 2);
                ss += __shfl_xor(ss, 4);
                float s = fminf(fmaxf(ss * inv_sqrt8, -CLAMP_V), CLAMP_V);
                float ex = __expf(s);
                den += ex;
                num = fmaf(ex, Vv + sc, num);
            }
        }
        // flush + trailing empty nodes
        if (cur >= 0)
            wV[(size_t)cur * 64 + lane] = num / (den + 1e-16f);
        for (int z = (cur < 0 ? n0 : cur + 1); z < n1; ++z)
            wV[(size_t)z * 64 + lane] = 0.f;
    }
}

extern "C" void kernel_launch(void* const* d_in, const int* in_sizes, int n_in,
                              void* d_out, int out_size, void* d_ws, size_t ws_size,
                              hipStream_t stream) {
    const float* x         = (const float*)d_in[0];
    const float* edge_attr = (const float*)d_in[1];
    const float* WQ        = (const float*)d_in[2];
    const float* bQ        = (const float*)d_in[3];
    const float* WK        = (const float*)d_in[4];
    const float* WVw       = (const float*)d_in[5];
    const float* WE1       = (const float*)d_in[6];
    const float* bE1       = (const float*)d_in[7];
    const int*   ei        = (const int*)d_in[8];

    float* out = (float*)d_out;
    float* wV = out;                          // [NN, 64]
    float* wE = out + (size_t)NN * 64;        // [NE, 64]

    float* Q        = (float*)d_ws;           // NN*64 f
    float* K        = Q + (size_t)NN * 64;
    float* V        = K + (size_t)NN * 64;
    int*   counts   = (int*)(V + (size_t)NN * 64);   // NN
    int*   row_ptr  = counts + NN;                   // NN+2 (pad for align)
    int*   cursor   = row_ptr + (NN + 2);            // NN
    int*   sortedE  = cursor + NN;                   // NE
    int*   workCtr  = sortedE + NE;                  // 2 ints
    int2*  sortedSD = (int2*)(workCtr + 2);          // NE int2

    hipMemsetAsync(counts,  0, (size_t)NN * sizeof(int), stream);
    hipMemsetAsync(workCtr, 0, 2 * sizeof(int), stream);

    proj_kernel<<<2048, 256, 0, stream>>>(x, WQ, bQ, WK, WVw, Q, K, V);
    hist_kernel<<<1024, 256, 0, stream>>>(ei, counts);
    scan_kernel<<<1, 1024, 0, stream>>>(counts, row_ptr, cursor);
    scatter_kernel<<<1024, 256, 0, stream>>>(ei, cursor, sortedE, sortedSD);
    edge_sorted_kernel<<<1024, 256, 0, stream>>>(edge_attr, WE1, bE1,
                                                 sortedE, sortedSD, row_ptr,
                                                 Q, K, V, wE, wV, workCtr);
}